// Round 1
// baseline (302.262 us; speedup 1.0000x reference)
//
#include <hip/hip_runtime.h>

#define V_VOCAB 50000
#define K_DIM   300
#define NROWS   1024
#define LEN     64
#define BN      128
#define NVB     391   // ceil(50000/128), covers 50048 cols (tail masked)

typedef __attribute__((ext_vector_type(8))) short bf16x8;
typedef __attribute__((ext_vector_type(4))) float f32x4;

static __device__ __forceinline__ unsigned short f2bf(float f) {
    unsigned int u = __builtin_bit_cast(unsigned int, f);
    u = u + 0x7fffu + ((u >> 16) & 1u);   // RNE
    return (unsigned short)(u >> 16);
}

// ---------------------------------------------------------------------------
// Kernel 1: samp_hid f32 [1024][300] -> bf16 a-fragment-swizzled buffer.
// Layout: frag (mblk, ks) lane l holds Z[mblk*16 + (l&15)][ks*32 + (l>>4)*8 + j]
// stored contiguously: ((mblk*10 + ks)*64 + l)*8 shorts  -> coalesced frag loads.
__global__ void zbf_kernel(const float* __restrict__ z, unsigned short* __restrict__ zbf) {
    int t = blockIdx.x * 256 + threadIdx.x;      // 0..40959
    if (t >= 64 * 10 * 64) return;
    int lane = t & 63;
    int rest = t >> 6;                           // mblk*10 + ks
    int ks   = rest % 10;
    int mblk = rest / 10;
    int row  = mblk * 16 + (lane & 15);
    int k0   = ks * 32 + (lane >> 4) * 8;
    unsigned short o[8];
#pragma unroll
    for (int j = 0; j < 8; ++j) {
        int k = k0 + j;
        float v = (k < K_DIM) ? z[row * K_DIM + k] : 0.0f;
        o[j] = f2bf(v);
    }
    ushort4* p = (ushort4*)(zbf + (size_t)t * 8);
    p[0] = make_ushort4(o[0], o[1], o[2], o[3]);
    p[1] = make_ushort4(o[4], o[5], o[6], o[7]);
}

// ---------------------------------------------------------------------------
// Kernel 2: per (side, v-tile of 128): partial[side][vb][row] = sum_{v in tile} exp(z_row . e_v + bias_v)
// E-tile resident in LDS (bf16, stride 328 to spread banks), A-frags in registers.
__launch_bounds__(512, 2)
__global__ void lse_gemm_kernel(const unsigned short* __restrict__ zbf,
                                const float* __restrict__ emb_x,
                                const float* __restrict__ emb_y,
                                const float* __restrict__ bias_x,
                                const float* __restrict__ bias_y,
                                float* __restrict__ partial) {
    __shared__ unsigned short Es[128 * 328];   // 83968 B
    __shared__ float Bs[128];
    __shared__ float red[512];

    const int tid  = threadIdx.x;
    const int side = blockIdx.y;
    const int vb   = blockIdx.x;
    const int v0   = vb * BN;
    const float* eg = side ? emb_y : emb_x;
    const float* bg = side ? bias_y : bias_x;

    // ---- stage E-tile: 128 rows x 320 cols (pad K 300->320 with 0, pad V with 0)
#pragma unroll
    for (int i = 0; i < 20; ++i) {
        int task = tid + i * 512;                // 0..10239 = 128 rows * 80 quads
        int row  = task / 80;
        int qc   = task - row * 80;
        int v    = v0 + row;
        ushort4 w = make_ushort4(0, 0, 0, 0);
        if (qc < 75 && v < V_VOCAB) {
            float4 f = *(const float4*)(eg + (size_t)v * K_DIM + qc * 4);
            w.x = f2bf(f.x); w.y = f2bf(f.y); w.z = f2bf(f.z); w.w = f2bf(f.w);
        }
        *(ushort4*)(&Es[row * 328 + qc * 4]) = w;
    }
    if (tid < 128) {
        int v = v0 + tid;
        Bs[tid] = (v < V_VOCAB) ? bg[v] : -1e30f;   // exp -> 0 for pad cols
    }
    __syncthreads();

    const int lane = tid & 63;
    const int wid  = tid >> 6;
    const int wm   = wid >> 1;     // 0..3 : 64-row band within 256-row pass
    const int wn   = wid & 1;      // 0..1 : 64-col half
    const int l15  = lane & 15;
    const int lg   = lane >> 4;    // 0..3

    for (int pass = 0; pass < 4; ++pass) {
        const int m0 = pass * 256;
        f32x4 acc[4][4];
#pragma unroll
        for (int mf = 0; mf < 4; ++mf)
#pragma unroll
            for (int nf = 0; nf < 4; ++nf)
                acc[mf][nf] = (f32x4){0.0f, 0.0f, 0.0f, 0.0f};

#pragma unroll
        for (int chunk = 0; chunk < 2; ++chunk) {
            bf16x8 a[4][5];
#pragma unroll
            for (int mf = 0; mf < 4; ++mf) {
                int mblk = (m0 + wm * 64 + mf * 16) >> 4;
#pragma unroll
                for (int ks = 0; ks < 5; ++ks) {
                    int ksg = chunk * 5 + ks;
                    a[mf][ks] = *(const bf16x8*)(zbf + ((size_t)(mblk * 10 + ksg) * 64 + lane) * 8);
                }
            }
#pragma unroll
            for (int ks = 0; ks < 5; ++ks) {
                const int kb = chunk * 160 + ks * 32 + lg * 8;
                bf16x8 b[4];
#pragma unroll
                for (int nf = 0; nf < 4; ++nf) {
                    int col = wn * 64 + nf * 16 + l15;
                    b[nf] = *(const bf16x8*)(&Es[col * 328 + kb]);
                }
#pragma unroll
                for (int mf = 0; mf < 4; ++mf)
#pragma unroll
                    for (int nf = 0; nf < 4; ++nf)
                        acc[mf][nf] = __builtin_amdgcn_mfma_f32_16x16x32_bf16(
                            a[mf][ks], b[nf], acc[mf][nf], 0, 0, 0);
            }
        }

        // ---- epilogue: exp(logit + bias), row-sum over this tile's 128 cols
        float s[4][4];
#pragma unroll
        for (int mf = 0; mf < 4; ++mf)
#pragma unroll
            for (int r = 0; r < 4; ++r) s[mf][r] = 0.0f;
#pragma unroll
        for (int mf = 0; mf < 4; ++mf)
#pragma unroll
            for (int nf = 0; nf < 4; ++nf) {
                float bv = Bs[wn * 64 + nf * 16 + l15];
#pragma unroll
                for (int r = 0; r < 4; ++r)
                    s[mf][r] += __expf(acc[mf][nf][r] + bv);
            }
#pragma unroll
        for (int mf = 0; mf < 4; ++mf)
#pragma unroll
            for (int r = 0; r < 4; ++r) {
                float v = s[mf][r];
                v += __shfl_xor(v, 1, 64);
                v += __shfl_xor(v, 2, 64);
                v += __shfl_xor(v, 4, 64);
                v += __shfl_xor(v, 8, 64);
                s[mf][r] = v;   // 64-col sum, replicated in 16-lane group
            }
        if (l15 == 0) {
#pragma unroll
            for (int mf = 0; mf < 4; ++mf)
#pragma unroll
                for (int r = 0; r < 4; ++r)
                    red[wn * 256 + wm * 64 + mf * 16 + lg * 4 + r] = s[mf][r];
        }
        __syncthreads();
        if (tid < 256)
            partial[((size_t)side * NVB + vb) * NROWS + m0 + tid] = red[tid] + red[256 + tid];
        __syncthreads();
    }
}

// ---------------------------------------------------------------------------
// Kernel 3: LSE[side][row] = log( sum_vb partial )
__global__ void lse_kernel(const float* __restrict__ partial, float* __restrict__ lse) {
    int g = blockIdx.x * 256 + threadIdx.x;   // 0..2047
    if (g >= 2048) return;
    int side = g >> 10, row = g & 1023;
    const float* p = partial + (size_t)side * NVB * NROWS + row;
    float s = 0.0f;
    for (int vb = 0; vb < NVB; ++vb) s += p[(size_t)vb * NROWS];
    lse[g] = logf(s);
}

// ---------------------------------------------------------------------------
// Kernel 4: exact f32 gathered logits: tok_logit[side][b][pos] = z_b . e_t + bias_t (0 if pad)
__global__ void gather_kernel(const float* __restrict__ z,
                              const int* __restrict__ tok_x, const int* __restrict__ tok_y,
                              const float* __restrict__ emb_x, const float* __restrict__ emb_y,
                              const float* __restrict__ bias_x, const float* __restrict__ bias_y,
                              float* __restrict__ tok_logit) {
    int p    = blockIdx.x * 4 + (threadIdx.x >> 6);   // 0..131071
    int lane = threadIdx.x & 63;
    int side = p >> 16;
    int r    = p & 65535;                              // b*64 + pos
    int b    = r >> 6;
    const int* tok = side ? tok_y : tok_x;
    int t = tok[r];
    float res = 0.0f;
    if (t != 0) {
        const float* eg = side ? emb_y : emb_x;
        const float* zr = z + (size_t)b * K_DIM;
        const float* er = eg + (size_t)t * K_DIM;
        float acc = 0.0f;
#pragma unroll
        for (int j = 0; j < 4; ++j) acc += zr[lane + j * 64] * er[lane + j * 64];
        if (lane < 44) acc += zr[lane + 256] * er[lane + 256];
#pragma unroll
        for (int off = 32; off > 0; off >>= 1) acc += __shfl_xor(acc, off, 64);
        res = acc + (side ? bias_y[t] : bias_x[t]);
    }
    if (lane == 0) tok_logit[p] = res;
}

// ---------------------------------------------------------------------------
// Kernel 5: nll_b = sum_sides cnt*LSE - sum(tok_logits); out = mean over 1024 rows
__global__ void finalize_kernel(const int* __restrict__ tok_x, const int* __restrict__ tok_y,
                                const float* __restrict__ tok_logit,
                                const float* __restrict__ lse,
                                float* __restrict__ out) {
    __shared__ float red[16];
    int b = threadIdx.x;   // 0..1023
    float v = 0.0f;
    for (int side = 0; side < 2; ++side) {
        const int*   tok = side ? tok_y : tok_x;
        const float* tl  = tok_logit + (size_t)side * 65536 + (size_t)b * 64;
        float s = 0.0f; int cnt = 0;
        for (int l = 0; l < 64; ++l) {
            if (tok[b * 64 + l] != 0) { cnt++; s += tl[l]; }
        }
        v += (float)cnt * lse[side * 1024 + b] - s;
    }
#pragma unroll
    for (int off = 32; off > 0; off >>= 1) v += __shfl_xor(v, off, 64);
    int wid = threadIdx.x >> 6, lane = threadIdx.x & 63;
    if (lane == 0) red[wid] = v;
    __syncthreads();
    if (threadIdx.x < 16) {
        float x = red[threadIdx.x];
#pragma unroll
        for (int off = 8; off > 0; off >>= 1) x += __shfl_xor(x, off, 64);
        if (threadIdx.x == 0) out[0] = x * (1.0f / 1024.0f);
    }
}

// ---------------------------------------------------------------------------
extern "C" void kernel_launch(void* const* d_in, const int* in_sizes, int n_in,
                              void* d_out, int out_size, void* d_ws, size_t ws_size,
                              hipStream_t stream) {
    const float* z      = (const float*)d_in[0];
    const int*   tok_x  = (const int*)d_in[1];
    const int*   tok_y  = (const int*)d_in[2];
    const float* emb_x  = (const float*)d_in[3];
    const float* emb_y  = (const float*)d_in[4];
    const float* bias_x = (const float*)d_in[5];
    const float* bias_y = (const float*)d_in[6];
    float* out = (float*)d_out;

    char* ws = (char*)d_ws;
    unsigned short* zbf   = (unsigned short*)ws;                       //   655,360 B
    float* partial        = (float*)(ws + 655360);                     // 3,203,072 B
    float* lse            = (float*)(ws + 655360 + 3203072);           //     8,192 B
    float* tok_logit      = (float*)(ws + 655360 + 3203072 + 8192);    //   524,288 B
                                                                       // total ~4.4 MB
    zbf_kernel<<<160, 256, 0, stream>>>(z, zbf);
    lse_gemm_kernel<<<dim3(NVB, 2), 512, 0, stream>>>(zbf, emb_x, emb_y, bias_x, bias_y, partial);
    lse_kernel<<<8, 256, 0, stream>>>(partial, lse);
    gather_kernel<<<32768, 256, 0, stream>>>(z, tok_x, tok_y, emb_x, emb_y, bias_x, bias_y, tok_logit);
    finalize_kernel<<<1, 1024, 0, stream>>>(tok_x, tok_y, tok_logit, lse, out);
}

// Round 2
// 191.396 us; speedup vs baseline: 1.5792x; 1.5792x over previous
//
#include <hip/hip_runtime.h>

#define V_VOCAB 50000
#define K_DIM   300
#define NROWS   1024
#define LEN     64
#define NBC     98      // col-blocks per side: 98*512 = 50176 >= 50000
#define CGS     784     // col-groups per side = NBC*8 waves
#define KS      19      // k-steps of 16: covers k=0..303 (300 dims + bias@300)

typedef __attribute__((ext_vector_type(8)))  short bf16x8;
typedef __attribute__((ext_vector_type(16))) float f32x16;

static __device__ __forceinline__ unsigned short f2bf(float f) {
    unsigned int u = __builtin_bit_cast(unsigned int, f);
    u = u + 0x7fffu + ((u >> 16) & 1u);   // RNE
    return (unsigned short)(u >> 16);
}

static __device__ __forceinline__ f32x16 zero16() {
    f32x16 z;
#pragma unroll
    for (int i = 0; i < 16; ++i) z[i] = 0.0f;
    return z;
}

// ---------------------------------------------------------------------------
// Kernel 1: samp_hid f32 [1024][300] -> bf16 B-fragment buffer for 32x32x16.
// Frag (rblk, ks): lane l holds Z[rblk*32 + (l&31)][ks*16 + (l>>5)*8 + j].
// k==300 -> 1.0 (bias slot), k>300 -> 0.
__global__ void zbf_kernel(const float* __restrict__ z, unsigned short* __restrict__ zbf) {
    int t = blockIdx.x * 256 + threadIdx.x;      // 0..38911 = 32 rblk * 19 ks * 64 lanes
    int l    = t & 63;
    int rest = t >> 6;
    int ks   = rest % KS;
    int rblk = rest / KS;
    int row  = rblk * 32 + (l & 31);
    int k0   = ks * 16 + (l >> 5) * 8;
    unsigned short o[8];
#pragma unroll
    for (int j = 0; j < 8; ++j) {
        int k = k0 + j;
        float v = (k < K_DIM) ? z[row * K_DIM + k] : ((k == K_DIM) ? 1.0f : 0.0f);
        o[j] = f2bf(v);
    }
    ushort4* p = (ushort4*)(zbf + (size_t)t * 8);
    p[0] = make_ushort4(o[0], o[1], o[2], o[3]);
    p[1] = make_ushort4(o[4], o[5], o[6], o[7]);
}

// ---------------------------------------------------------------------------
// Kernel 2: D[c][m] = sum_k E[c][k]*Z[m][k] (+bias via k=300), then
// partial[cg][m] = sum over the wave's 64 vocab cols of exp(D).
// E a-frags in registers (wave owns 64 cols x K); Z b-frags from LDS,
// double-buffered, staged issue-early/write-late. One barrier per 64-row pass.
__launch_bounds__(512, 2)
__global__ void gemm_kernel(const unsigned short* __restrict__ zbf,
                            const float* __restrict__ emb_x,
                            const float* __restrict__ emb_y,
                            const float* __restrict__ bias_x,
                            const float* __restrict__ bias_y,
                            float* __restrict__ partial) {
    __shared__ unsigned short Zs[2][19456];   // 2 x 38,912 B

    const int tid  = threadIdx.x;
    const int lane = tid & 63;
    const int w    = tid >> 6;
    const int side = blockIdx.y;
    const int bc   = blockIdx.x;
    const float* eg = side ? emb_y : emb_x;
    const float* bg = side ? bias_y : bias_x;
    const int c0 = bc * 512 + w * 64;

    // ---- load E a-fragments into registers (once per block)
    bf16x8 a[2][KS];
#pragma unroll
    for (int cb = 0; cb < 2; ++cb) {
        const int c = c0 + cb * 32 + (lane & 31);
        const bool cv = (c < V_VOCAB);
        const float* erow = eg + (size_t)c * K_DIM;
        const int khi = (lane >> 5) * 8;
#pragma unroll
        for (int ks = 0; ks < KS; ++ks) {
            const int k0 = ks * 16 + khi;
            float f[8];
            if (k0 + 8 <= K_DIM) {
                float4 u  = cv ? *(const float4*)(erow + k0)     : make_float4(0, 0, 0, 0);
                float4 v2 = cv ? *(const float4*)(erow + k0 + 4) : make_float4(0, 0, 0, 0);
                f[0] = u.x;  f[1] = u.y;  f[2] = u.z;  f[3] = u.w;
                f[4] = v2.x; f[5] = v2.y; f[6] = v2.z; f[7] = v2.w;
            } else {
#pragma unroll
                for (int j = 0; j < 8; ++j) {
                    int k = k0 + j;
                    f[j] = (k < K_DIM) ? (cv ? erow[k] : 0.0f)
                         : (k == K_DIM ? (cv ? bg[c] : -3e38f) : 0.0f);
                }
            }
            bf16x8 t;
#pragma unroll
            for (int j = 0; j < 8; ++j) t[j] = (short)f2bf(f[j]);
            a[cb][ks] = t;
        }
    }

    const int cg = (side * NBC + bc) * 8 + w;
    float* pout = partial + (size_t)cg * NROWS;

    // ---- prologue: stage pass 0 (rows 0..63) into Zs[0]
    uint4 st[5];
    {
        const uint4* src = (const uint4*)zbf;
#pragma unroll
        for (int i = 0; i < 5; ++i) { int idx = i * 512 + tid; if (idx < 2432) st[i] = src[idx]; }
        uint4* dst = (uint4*)&Zs[0][0];
#pragma unroll
        for (int i = 0; i < 5; ++i) { int idx = i * 512 + tid; if (idx < 2432) dst[i * 512 + tid] = st[i]; }
    }
    __syncthreads();

    int buf = 0;
    for (int p = 0; p < 16; ++p) {
        // issue next pass's loads early (lands during compute)
        if (p < 15) {
            const uint4* src = (const uint4*)(zbf + (size_t)(p + 1) * 19456);
#pragma unroll
            for (int i = 0; i < 5; ++i) { int idx = i * 512 + tid; if (idx < 2432) st[i] = src[idx]; }
        }

        const unsigned short* zb = &Zs[buf][0];
        f32x16 acc00 = zero16(), acc01 = zero16(), acc10 = zero16(), acc11 = zero16();
#pragma unroll
        for (int ks = 0; ks < KS; ++ks) {
            bf16x8 b0 = *(const bf16x8*)(zb + ((size_t)ks * 64 + lane) * 8);
            bf16x8 b1 = *(const bf16x8*)(zb + ((size_t)(KS + ks) * 64 + lane) * 8);
            acc00 = __builtin_amdgcn_mfma_f32_32x32x16_bf16(a[0][ks], b0, acc00, 0, 0, 0);
            acc01 = __builtin_amdgcn_mfma_f32_32x32x16_bf16(a[0][ks], b1, acc01, 0, 0, 0);
            acc10 = __builtin_amdgcn_mfma_f32_32x32x16_bf16(a[1][ks], b0, acc10, 0, 0, 0);
            acc11 = __builtin_amdgcn_mfma_f32_32x32x16_bf16(a[1][ks], b1, acc11, 0, 0, 0);
        }

        // epilogue: exp + per-lane sum over 32 vocab rows, + cross-half add
        float s0 = 0.0f, s1 = 0.0f;
#pragma unroll
        for (int r = 0; r < 16; ++r) {
            s0 += __expf(acc00[r]) + __expf(acc10[r]);
            s1 += __expf(acc01[r]) + __expf(acc11[r]);
        }
        float t0 = s0 + __shfl_xor(s0, 32, 64);
        float t1 = s1 + __shfl_xor(s1, 32, 64);
        pout[p * 64 + lane] = (lane < 32) ? t0 : t1;

        // write staged data late (T14), then single barrier per pass
        if (p < 15) {
            uint4* dst = (uint4*)&Zs[buf ^ 1][0];
#pragma unroll
            for (int i = 0; i < 5; ++i) { int idx = i * 512 + tid; if (idx < 2432) dst[i * 512 + tid] = st[i]; }
        }
        __syncthreads();
        buf ^= 1;
    }
}

// ---------------------------------------------------------------------------
// Kernel 3: LSE[side][m] = log( sum_cg partial[cg][m] )
__global__ void lse_kernel(const float* __restrict__ partial, float* __restrict__ lse) {
    __shared__ float r4[4];
    int bx = blockIdx.x;                  // 0..2047
    int side = bx >> 10, m = bx & 1023;
    const float* p = partial + (size_t)side * CGS * NROWS + m;
    float s = 0.0f;
    for (int i = threadIdx.x; i < CGS; i += 256) s += p[(size_t)i * NROWS];
#pragma unroll
    for (int off = 32; off > 0; off >>= 1) s += __shfl_xor(s, off, 64);
    if ((threadIdx.x & 63) == 0) r4[threadIdx.x >> 6] = s;
    __syncthreads();
    if (threadIdx.x == 0) lse[bx] = logf(r4[0] + r4[1] + r4[2] + r4[3]);
}

// ---------------------------------------------------------------------------
// Kernel 4: gather-SUM: g_b = sum_{valid pos} e_t ; then
// nllpart[side][b] = cnt*LSE - (z_b . g_b + sum bias_t)
__global__ void gatherdot_kernel(const float* __restrict__ z,
                                 const int* __restrict__ tok_x, const int* __restrict__ tok_y,
                                 const float* __restrict__ emb_x, const float* __restrict__ emb_y,
                                 const float* __restrict__ bias_x, const float* __restrict__ bias_y,
                                 const float* __restrict__ lse, float* __restrict__ nllpart) {
    __shared__ float gs[304];
    const int b = blockIdx.x, side = blockIdx.y, tid = threadIdx.x;
    const int* tokp = (side ? tok_y : tok_x) + b * LEN;
    const float* eg = side ? emb_y : emb_x;
    if (tid < K_DIM) {
        float g0 = 0.0f, g1 = 0.0f;
#pragma unroll 2
        for (int pos = 0; pos < LEN; pos += 2) {
            int t0 = tokp[pos], t1 = tokp[pos + 1];
            if (t0) g0 += eg[(size_t)t0 * K_DIM + tid];
            if (t1) g1 += eg[(size_t)t1 * K_DIM + tid];
        }
        gs[tid] = g0 + g1;
    }
    __syncthreads();
    if (tid < 64) {
        const float* bg = side ? bias_y : bias_x;
        float dp = 0.0f;
#pragma unroll
        for (int i = 0; i < 5; ++i) {
            int d = tid + i * 64;
            if (d < K_DIM) dp += z[(size_t)b * K_DIM + d] * gs[d];
        }
        int t = tokp[tid];
        float bs = t ? bg[t] : 0.0f;
        float ct = t ? 1.0f : 0.0f;
#pragma unroll
        for (int off = 32; off > 0; off >>= 1) {
            dp += __shfl_xor(dp, off, 64);
            bs += __shfl_xor(bs, off, 64);
            ct += __shfl_xor(ct, off, 64);
        }
        if (tid == 0) nllpart[side * NROWS + b] = ct * lse[side * NROWS + b] - dp - bs;
    }
}

// ---------------------------------------------------------------------------
// Kernel 5: out = mean over b of (nll_x + nll_y)
__global__ void finalize_kernel(const float* __restrict__ nllpart, float* __restrict__ out) {
    __shared__ float r16[16];
    int i = threadIdx.x;   // 0..1023
    float v = nllpart[i] + nllpart[NROWS + i];
#pragma unroll
    for (int off = 32; off > 0; off >>= 1) v += __shfl_xor(v, off, 64);
    if ((i & 63) == 0) r16[i >> 6] = v;
    __syncthreads();
    if (i < 64) {
        float x = (i < 16) ? r16[i] : 0.0f;
#pragma unroll
        for (int off = 8; off > 0; off >>= 1) x += __shfl_xor(x, off, 64);
        if (i == 0) out[0] = x * (1.0f / 1024.0f);
    }
}

// ---------------------------------------------------------------------------
extern "C" void kernel_launch(void* const* d_in, const int* in_sizes, int n_in,
                              void* d_out, int out_size, void* d_ws, size_t ws_size,
                              hipStream_t stream) {
    const float* z      = (const float*)d_in[0];
    const int*   tok_x  = (const int*)d_in[1];
    const int*   tok_y  = (const int*)d_in[2];
    const float* emb_x  = (const float*)d_in[3];
    const float* emb_y  = (const float*)d_in[4];
    const float* bias_x = (const float*)d_in[5];
    const float* bias_y = (const float*)d_in[6];
    float* out = (float*)d_out;

    char* ws = (char*)d_ws;
    unsigned short* zbf = (unsigned short*)ws;                        //   622,592 B
    float* partial      = (float*)(ws + 622592);                      // 6,422,528 B
    float* lse          = (float*)(ws + 622592 + 6422528);            //     8,192 B
    float* nllpart      = (float*)(ws + 622592 + 6422528 + 8192);     //     8,192 B
                                                                      // total ~7.06 MB
    zbf_kernel<<<152, 256, 0, stream>>>(z, zbf);
    gemm_kernel<<<dim3(NBC, 2), 512, 0, stream>>>(zbf, emb_x, emb_y, bias_x, bias_y, partial);
    lse_kernel<<<2048, 256, 0, stream>>>(partial, lse);
    gatherdot_kernel<<<dim3(NROWS, 2), 320, 0, stream>>>(z, tok_x, tok_y, emb_x, emb_y,
                                                         bias_x, bias_y, lse, nllpart);
    finalize_kernel<<<1, 1024, 0, stream>>>(nllpart, out);
}